// Round 4
// baseline (342.995 us; speedup 1.0000x reference)
//
#include <hip/hip_runtime.h>

using u16 = unsigned short;
using u32 = unsigned int;

typedef __attribute__((ext_vector_type(4))) float f32x4;
typedef __attribute__((ext_vector_type(8))) short s16x8;

__device__ __forceinline__ u16 f2b(float f) {
  u32 u = __builtin_bit_cast(u32, f);
  u += 0x7FFFu + ((u >> 16) & 1u);
  return (u16)(u >> 16);
}
__device__ __forceinline__ float b2f(u16 h) {
  return __builtin_bit_cast(float, (u32)h << 16);
}
__device__ __forceinline__ void gl_lds16(const void* g, void* l) {
  __builtin_amdgcn_global_load_lds(
      (const __attribute__((address_space(1))) void*)g,
      (__attribute__((address_space(3))) void*)l, 16, 0, 0);
}
template<int N> __device__ __forceinline__ void waitvm() {
  static_assert(N == 8 || N == 4 || N == 0, "literal");
  if constexpr (N == 8)      asm volatile("s_waitcnt vmcnt(8)" ::: "memory");
  else if constexpr (N == 4) asm volatile("s_waitcnt vmcnt(4)" ::: "memory");
  else                       asm volatile("s_waitcnt vmcnt(0)" ::: "memory");
}
// raw barrier + compiler fence: no LDS access or global_load_lds may be
// reordered across it by the optimizer.
__device__ __forceinline__ void barrier_np() {
  __builtin_amdgcn_s_barrier();
  asm volatile("" ::: "memory");
}

// ---- fused fp32 -> bf16 conversion: x | Wq | Wk | Wv -> contiguous dst ------
__global__ __launch_bounds__(256) void convert4_k(
    const float* __restrict__ x, const float* __restrict__ Wq,
    const float* __restrict__ Wk, const float* __restrict__ Wv,
    u16* __restrict__ dst) {
  long g = (long)(blockIdx.x * 256 + threadIdx.x) * 8;   // 8-elem chunks
  const float* s;
  if (g < 8388608L)       s = x  + g;
  else if (g < 9437184L)  s = Wq + (g - 8388608L);
  else if (g < 10485760L) s = Wk + (g - 9437184L);
  else                    s = Wv + (g - 10485760L);
  f32x4 lo = *(const f32x4*)s;
  f32x4 hi = *(const f32x4*)(s + 4);
  s16x8 o;
  #pragma unroll
  for (int e = 0; e < 4; ++e) { o[e] = (short)f2b(lo[e]); o[4 + e] = (short)f2b(hi[e]); }
  *(s16x8*)(dst + g) = o;
}

// ---- NT GEMM, 128x128 tile, BK=32, 4-slot LDS ring, reg-frag prefetch -------
// Body T (one barrier per K-tile):
//   waitvm<4>  -> tile T+1's stage landed (mine; only T+2's 4 loads in flight)
//   s_barrier  -> tile T+1 landed for ALL waves (each drained its own vmcnt
//                 before arriving); also: all waves' frag reads of tile T-1
//                 (issued in body T-2, drained before body T-1's MFMAs)
//                 completed -> slot (T+3)&3 == (T-1)&3 is WAR-safe
//   stage T+3  -> 4 global_load_lds into slot (T-1)&3
//   read frags of tile T+1 into the spare register set (no consumer this body)
//   16 MFMA on tile T's frags -- IN REGISTERS SINCE BODY T-1: the MFMA
//                 cluster never waits on LDS; next-tile reads co-issue with it
// vmcnt never drains to 0 until the last two bodies (T >= NT-2).
// Register ping-pong via unroll-by-2 (static indexing only, no scratch).
// Bank swizzle (row stride 64 B): LDS chunk (r,c) holds global chunk
// c ^ ((r>>1)&3); b128 frag reads measured conflict-free (rounds 2-3: 0).
// EPI 0: QKV proj (+bias; bf16 Q[b][s][h], K[b][s][h], Vt[b][d][s]).
// EPI 1: scores (*1/32, mask==0 -> -inf).  EPI 2: PV -> fp32 out.
template<int EPI>
__global__ __launch_bounds__(256, 2) void gemm_nt(
    const u16* __restrict__ A, const u16* __restrict__ B0,
    const u16* __restrict__ W2, const u16* __restrict__ W3,
    int lda, int ldb, int K, long za, long zb, long ze,
    const float* __restrict__ bq, const float* __restrict__ bk, const float* __restrict__ bv,
    u16* __restrict__ qw, u16* __restrict__ kw, u16* __restrict__ vt,
    const int* __restrict__ mask, u16* __restrict__ sc, float* __restrict__ outO)
{
  constexpr int ACH   = 512;             // A: 128 rows * 4 chunks of 16B
  constexpr int CH    = 1024;            // + B: 128 rows * 4 chunks
  constexpr int CALLS = 4;               // CH / 256 threads
  constexpr int SLOT  = CH * 8;          // u16 per ring slot (16 KB)
  __shared__ __align__(16) u16 lds[4 * SLOT];   // 64 KB -> 2 blocks/CU

  const int tid  = threadIdx.x;
  const int wave = tid >> 6, lane = tid & 63;
  const int wr = wave >> 1, wc = wave & 1;
  const int m0 = blockIdx.y * 128, n0 = blockIdx.x * 128;
  const long z = blockIdx.z;
  A += z * za;

  const u16* Bsrc = B0;
  int nbase = n0;
  if constexpr (EPI == 0) {
    Bsrc = (n0 < 1024) ? B0 : (n0 < 2048) ? W2 : W3;
    nbase = n0 & 1023;
  }
  Bsrc += z * zb;

  // per-call staging source pointers (at k=0) and linear LDS offsets.
  // global source is per-lane (swizzled); LDS dest is linear (HW lane*16B).
  const u16* gsrc[CALLS];
  u32 loff[CALLS];
  #pragma unroll
  for (int c = 0; c < CALLS; ++c) {
    int qq  = c * 256 + tid;             // 16B chunk id within tile
    int isB = qq >= ACH;
    int r   = (isB ? qq - ACH : qq) >> 2;
    int kc  = (qq & 3) ^ ((r >> 1) & 3); // XOR-swizzled source chunk
    gsrc[c] = (isB ? (Bsrc + (size_t)(nbase + r) * ldb)
                   : (A    + (size_t)(m0    + r) * lda)) + kc * 8;
    loff[c] = (u32)qq * 8;
  }

  // fragment read offsets (u16 units, relative to ring-slot base)
  const int frow = lane & 15;            // m (or n) index within 16x16 tile
  const int q    = lane >> 4;            // k-quarter (8 elems)
  u32 aoff[4], boff[4];
  #pragma unroll
  for (int i = 0; i < 4; ++i) {
    int lr = wr * 64 + i * 16 + frow;
    aoff[i] = (u32)lr * 32 + (u32)((q ^ ((lr >> 1) & 3)) << 3);
  }
  #pragma unroll
  for (int j = 0; j < 4; ++j) {
    int lc = wc * 64 + j * 16 + frow;
    boff[j] = (u32)ACH * 8 + (u32)lc * 32 + (u32)((q ^ ((lc >> 1) & 3)) << 3);
  }

  f32x4 acc[4][4];
  const f32x4 fz = {0.f, 0.f, 0.f, 0.f};
  #pragma unroll
  for (int i = 0; i < 4; ++i)
    #pragma unroll
    for (int j = 0; j < 4; ++j) acc[i][j] = fz;

  const int NT = K >> 5;                 // BK=32 tiles (32 or 64; even, >= 8)

  auto body = [&](int T, s16x8 (&ca)[4], s16x8 (&cb)[4],
                  s16x8 (&na)[4], s16x8 (&nb)[4], bool stg, bool rd) {
    if (T < NT - 2) waitvm<CALLS>(); else waitvm<0>();
    barrier_np();
    if (stg) {
      u16* sb = lds + (size_t)((T + 3) & 3) * SLOT;
      const size_t koff = (size_t)(T + 3) * 32;
      #pragma unroll
      for (int c = 0; c < CALLS; ++c) gl_lds16(gsrc[c] + koff, sb + loff[c]);
    }
    if (rd) {                            // frags of tile T+1 -> spare set
      const u16* nbuf = lds + (size_t)((T + 1) & 3) * SLOT;
      #pragma unroll
      for (int j = 0; j < 4; ++j) nb[j] = *(const s16x8*)(nbuf + boff[j]);
      #pragma unroll
      for (int i = 0; i < 4; ++i) na[i] = *(const s16x8*)(nbuf + aoff[i]);
    }
    __builtin_amdgcn_s_setprio(1);       // tile T's frags: in regs already
    #pragma unroll
    for (int i = 0; i < 4; ++i)
      #pragma unroll
      for (int j = 0; j < 4; ++j)
        acc[i][j] = __builtin_amdgcn_mfma_f32_16x16x32_bf16(ca[i], cb[j], acc[i][j], 0, 0, 0);
    __builtin_amdgcn_s_setprio(0);
  };

  // prologue: 3 tiles staged; read tile 0's frags into set f
  #pragma unroll
  for (int c = 0; c < CALLS; ++c) gl_lds16(gsrc[c],      lds            + loff[c]);
  #pragma unroll
  for (int c = 0; c < CALLS; ++c) gl_lds16(gsrc[c] + 32, lds + SLOT     + loff[c]);
  #pragma unroll
  for (int c = 0; c < CALLS; ++c) gl_lds16(gsrc[c] + 64, lds + 2 * SLOT + loff[c]);
  waitvm<8>();                           // tile 0 landed (tiles 1,2 in flight)
  barrier_np();
  s16x8 fa[4], fb[4], ga[4], gb[4];
  #pragma unroll
  for (int j = 0; j < 4; ++j) fb[j] = *(const s16x8*)(lds + boff[j]);
  #pragma unroll
  for (int i = 0; i < 4; ++i) fa[i] = *(const s16x8*)(lds + aoff[i]);

  for (int T = 0; T < NT; T += 2) {      // register ping-pong, unroll-by-2
    body(T,     fa, fb, ga, gb, T     < NT - 3, true);
    body(T + 1, ga, gb, fa, fb, T + 1 < NT - 3, T + 2 < NT);
  }

  // epilogue: C/D layout col=lane&15, row=(lane>>4)*4+reg  (m89-verified)
  const int r0 = (lane >> 4) * 4;
  const int ccol = lane & 15;
  #pragma unroll
  for (int i = 0; i < 4; ++i) {
    #pragma unroll
    for (int j = 0; j < 4; ++j) {
      #pragma unroll
      for (int r = 0; r < 4; ++r) {
        int R = m0 + wr * 64 + i * 16 + r0 + r;           // row: (b,)s / q idx
        int C = n0 + wc * 64 + j * 16 + ccol;             // col: feature/k/d
        float v = acc[i][j][r];
        if constexpr (EPI == 0) {
          int sec = C >> 10, nl = C & 1023;
          v += (sec == 0) ? bq[nl] : (sec == 1) ? bk[nl] : bv[nl];
          u16 o = f2b(v);
          int b = R >> 11, s = R & 2047;
          if (sec == 0)      qw[(size_t)R * 1024 + nl] = o;               // Q[b][s][h]
          else if (sec == 1) kw[(size_t)R * 1024 + nl] = o;               // K[b][s][h]
          else               vt[(size_t)b * 2097152u + (size_t)nl * 2048 + s] = o; // Vt[b][d][s]
        } else if constexpr (EPI == 1) {
          v *= 0.03125f;  // 1/sqrt(1024)
          size_t idx = (size_t)(z * ze) + (size_t)R * 2048 + C;
          if (mask[idx] == 0) v = -__builtin_inff();
          sc[idx] = f2b(v);
        } else {
          outO[(size_t)(z * ze) + (size_t)R * 1024 + C] = v;   // fp32 out
        }
      }
    }
  }
}

// ---- row softmax over 2048 bf16, in place, fp32 internal --------------------
__global__ __launch_bounds__(256) void softmax_k(u16* __restrict__ Sc) {
  __shared__ float red[8];
  u16* p = Sc + (size_t)blockIdx.x * 2048;
  const int tid = threadIdx.x;
  const int lane = tid & 63, wv = tid >> 6;
  s16x8 u = *(const s16x8*)(p + tid * 8);
  float v[8];
  #pragma unroll
  for (int e = 0; e < 8; ++e) v[e] = b2f((u16)u[e]);
  float mx = v[0];
  #pragma unroll
  for (int e = 1; e < 8; ++e) mx = fmaxf(mx, v[e]);
  #pragma unroll
  for (int off = 32; off > 0; off >>= 1) mx = fmaxf(mx, __shfl_xor(mx, off));
  if (lane == 0) red[wv] = mx;
  __syncthreads();
  mx = fmaxf(fmaxf(red[0], red[1]), fmaxf(red[2], red[3]));
  float s = 0.f;
  #pragma unroll
  for (int e = 0; e < 8; ++e) { v[e] = __expf(v[e] - mx); s += v[e]; }
  #pragma unroll
  for (int off = 32; off > 0; off >>= 1) s += __shfl_xor(s, off);
  if (lane == 0) red[4 + wv] = s;
  __syncthreads();
  s = (red[4] + red[5]) + (red[6] + red[7]);
  float inv = 1.f / s;
  s16x8 o;
  #pragma unroll
  for (int e = 0; e < 8; ++e) o[e] = (short)f2b(v[e] * inv);
  *(s16x8*)(p + tid * 8) = o;
}

extern "C" void kernel_launch(void* const* d_in, const int* in_sizes, int n_in,
                              void* d_out, int out_size, void* d_ws, size_t ws_size,
                              hipStream_t stream) {
  const float* x  = (const float*)d_in[0];
  const int* mask = (const int*)d_in[1];
  const float* Wq = (const float*)d_in[2];
  const float* bq = (const float*)d_in[3];
  const float* Wk = (const float*)d_in[4];
  const float* bk = (const float*)d_in[5];
  const float* Wv = (const float*)d_in[6];
  const float* bv = (const float*)d_in[7];
  float* out = (float*)d_out;
  char* ws = (char*)d_ws;   // ws_size >= 104 MB established previously

  u16* xc  = (u16*)ws;                   // [8192][1024]  16 MB
  u16* Wqc = (u16*)(ws + (16u << 20));   // 2 MB each (contiguous after xc)
  u16* Wkc = (u16*)(ws + (18u << 20));
  u16* Wvc = (u16*)(ws + (20u << 20));
  u16* Qw  = (u16*)(ws + (22u << 20));   // [4][2048][1024] 16 MB
  u16* Kw  = (u16*)(ws + (38u << 20));   // 16 MB
  u16* Vt  = (u16*)(ws + (54u << 20));   // [4][1024][2048] 16 MB
  u16* Sc  = (u16*)(ws + (70u << 20));   // [4][2048][2048] 32 MB -> 102 MB

  convert4_k<<<5632, 256, 0, stream>>>(x, Wq, Wk, Wv, xc);

  // QKV: M=8192, N=3072, K=1024.  128x128 -> 1536 blocks @2/CU = 3 rounds
  gemm_nt<0><<<dim3(24, 64, 1), 256, 0, stream>>>(
      xc, Wqc, Wkc, Wvc, 1024, 1024, 1024, 0, 0, 0,
      bq, bk, bv, Qw, Kw, Vt, nullptr, nullptr, nullptr);
  // scores: per-z M=2048, N=2048, K=1024.  128x128 -> 1024 blocks @2/CU
  gemm_nt<1><<<dim3(16, 16, 4), 256, 0, stream>>>(
      Qw, Kw, nullptr, nullptr, 1024, 1024, 1024, 2097152, 2097152, 4194304,
      nullptr, nullptr, nullptr, nullptr, nullptr, nullptr, mask, Sc, nullptr);
  softmax_k<<<8192, 256, 0, stream>>>(Sc);
  // PV: per-z M=2048, N=1024, K=2048.  128x128 -> 512 blocks @2/CU
  gemm_nt<2><<<dim3(8, 16, 4), 256, 0, stream>>>(
      Sc, Vt, nullptr, nullptr, 2048, 2048, 2048, 4194304, 2097152, 2097152,
      nullptr, nullptr, nullptr, nullptr, nullptr, nullptr, nullptr, nullptr, out);
}

// Round 5
// 334.472 us; speedup vs baseline: 1.0255x; 1.0255x over previous
//
#include <hip/hip_runtime.h>

using u16 = unsigned short;
using u32 = unsigned int;

typedef __attribute__((ext_vector_type(4))) float f32x4;
typedef __attribute__((ext_vector_type(8))) short s16x8;

__device__ __forceinline__ u16 f2b(float f) {
  u32 u = __builtin_bit_cast(u32, f);
  u += 0x7FFFu + ((u >> 16) & 1u);
  return (u16)(u >> 16);
}
__device__ __forceinline__ float b2f(u16 h) {
  return __builtin_bit_cast(float, (u32)h << 16);
}
__device__ __forceinline__ void gl_lds16(const void* g, void* l) {
  __builtin_amdgcn_global_load_lds(
      (const __attribute__((address_space(1))) void*)g,
      (__attribute__((address_space(3))) void*)l, 16, 0, 0);
}
template<int N> __device__ __forceinline__ void waitvm() {
  static_assert(N == 4 || N == 0, "literal");
  if constexpr (N == 4) asm volatile("s_waitcnt vmcnt(4)" ::: "memory");
  else                  asm volatile("s_waitcnt vmcnt(0)" ::: "memory");
}
// raw barrier + compiler fence (no reordering of LDS/global_load_lds across).
__device__ __forceinline__ void barrier_np() {
  __builtin_amdgcn_s_barrier();
  asm volatile("" ::: "memory");
}

// ---- fused fp32 -> bf16 conversion: x | Wq | Wk | Wv -> contiguous dst ------
__global__ __launch_bounds__(256) void convert4_k(
    const float* __restrict__ x, const float* __restrict__ Wq,
    const float* __restrict__ Wk, const float* __restrict__ Wv,
    u16* __restrict__ dst) {
  long g = (long)(blockIdx.x * 256 + threadIdx.x) * 8;   // 8-elem chunks
  const float* s;
  if (g < 8388608L)       s = x  + g;
  else if (g < 9437184L)  s = Wq + (g - 8388608L);
  else if (g < 10485760L) s = Wk + (g - 9437184L);
  else                    s = Wv + (g - 10485760L);
  f32x4 lo = *(const f32x4*)s;
  f32x4 hi = *(const f32x4*)(s + 4);
  s16x8 o;
  #pragma unroll
  for (int e = 0; e < 4; ++e) { o[e] = (short)f2b(lo[e]); o[4 + e] = (short)f2b(hi[e]); }
  *(s16x8*)(dst + g) = o;
}

// ---- NT GEMM, m201-style 4-phase K-tiles: BMx256 tile, BK=64, 2-buf LDS -----
// 8 waves (2 x 4), wave-tile (BM/2)x64.  Per K-tile t (buf b = t&1), 4 phases:
//   phase p: ds_read A-frags for row-quadrant p (p0 also reads ALL B-frags);
//            stage one half-tile: p0/p1 -> A-lo/hi(t+1) into buf b^1 (its A
//            slots were last read at tile t-1, drained before t-1.p3's 2nd
//            barrier);  p2/p3 -> B-lo/hi(t+2) into buf b (B slots of buf b
//            are only read at t.p0, drained before t.p0's 2nd barrier);
//            p3 only: s_waitcnt vmcnt(4)  -> everything except B(t+2)'s 4
//            loads has landed == tile t+1 is fully in LDS (for me);
//            barrier  (collectivizes the per-wave vmcnt guarantee);
//            setprio(1); quadrant MFMA cluster x K=64; setprio(0);
//            barrier  (all waves' frag reads of this phase are complete --
//            each wave's lgkmcnt(0) precedes its MFMAs -- so the next
//            phase's stage cannot overwrite data still being read).
// vmcnt never drains to 0 until the tail (t+2 >= NT).  One vmcnt per K-tile.
// Bank swizzle (128 B rows): chunk c' = c ^ (row&7) on BOTH stage-source and
// frag-read -> 16-lane frag read spreads over 8 16B-groups, 2-way = free.
// EPI 0: QKV proj (+bias; bf16 Q[b][s][h], K[b][s][h], Vt[b][d][s]).
// EPI 1: scores (*1/32, mask==0 -> -inf).  EPI 2: PV -> fp32 out.
template<int EPI, int MREP>   // MREP = BM/32 (4 or 8)
__global__ __launch_bounds__(512, 2) void gemm_nt(
    const u16* __restrict__ A, const u16* __restrict__ B0,
    const u16* __restrict__ W2, const u16* __restrict__ W3,
    int lda, int ldb, int K, long za, long zb, long ze,
    const float* __restrict__ bq, const float* __restrict__ bk, const float* __restrict__ bv,
    u16* __restrict__ qw, u16* __restrict__ kw, u16* __restrict__ vt,
    const int* __restrict__ mask, u16* __restrict__ sc, float* __restrict__ outO)
{
  constexpr int BM   = 32 * MREP;        // 128 or 256
  constexpr int WR   = 16 * MREP;        // wave rows (64 or 128)
  constexpr int RT   = MREP / 4;         // row-tiles per phase (1 or 2)
  constexpr int AU   = BM * 64;          // u16 per A buffer (BM rows x 64 k)
  constexpr int BU   = 256 * 64;         // u16 per B buffer
  constexpr int BUFU = AU + BU;
  constexpr int ACH  = BM / 128;         // gl_lds calls per A half-tile (1|2)
  __shared__ __align__(16) u16 lds[2 * BUFU];   // 96 KB or 128 KB

  const int tid  = threadIdx.x;
  const int wave = tid >> 6, lane = tid & 63;
  const int wr = wave >> 2, wc = wave & 3;          // 2 x 4 wave grid
  const int m0 = blockIdx.y * BM, n0 = blockIdx.x * 256;
  const long z = blockIdx.z;
  A += z * za;

  const u16* Bsrc = B0;
  int nbase = n0;
  if constexpr (EPI == 0) {
    Bsrc = (n0 < 1024) ? B0 : (n0 < 2048) ? W2 : W3;
    nbase = n0 & 1023;
  }
  Bsrc += z * zb;

  // staging source pointers (swizzled global col-chunk; linear LDS dest)
  const u16* pA[2 * ACH];
  #pragma unroll
  for (int hc = 0; hc < 2 * ACH; ++hc) {
    int qq = hc * 512 + tid;             // 16B chunk id within A K-tile
    int r  = qq >> 3;
    int cc = (qq & 7) ^ (r & 7);
    pA[hc] = A + (size_t)(m0 + r) * lda + cc * 8;
  }
  const u16* pB[4];
  #pragma unroll
  for (int hc = 0; hc < 4; ++hc) {
    int qq = hc * 512 + tid;
    int r  = qq >> 3;
    int cc = (qq & 7) ^ (r & 7);
    pB[hc] = Bsrc + (size_t)(nbase + r) * ldb + cc * 8;
  }

  // fragment read offsets (u16 units, relative to lds base)
  const int frow = lane & 15;            // m (or n) index within 16x16 tile
  const int lq   = lane >> 4;            // k-quarter (8 elems of 32-k step)
  u32 aoff[MREP][2], boff[4][2];
  #pragma unroll
  for (int rt = 0; rt < MREP; ++rt) {
    int lr = wr * WR + rt * 16 + frow;
    #pragma unroll
    for (int s = 0; s < 2; ++s)
      aoff[rt][s] = (u32)lr * 64 + (u32)(((s * 4 + lq) ^ (lr & 7)) << 3);
  }
  #pragma unroll
  for (int j = 0; j < 4; ++j) {
    int lc = wc * 64 + j * 16 + frow;
    #pragma unroll
    for (int s = 0; s < 2; ++s)
      boff[j][s] = (u32)AU + (u32)lc * 64 + (u32)(((s * 4 + lq) ^ (lc & 7)) << 3);
  }

  f32x4 acc[MREP][4];
  const f32x4 fz = {0.f, 0.f, 0.f, 0.f};
  #pragma unroll
  for (int i = 0; i < MREP; ++i)
    #pragma unroll
    for (int j = 0; j < 4; ++j) acc[i][j] = fz;

  const int NT = K >> 6;                 // BK=64 K-tiles (16 or 32)

  auto stageA = [&](int t, int h) {      // A half h of tile t -> buf t&1
    u16* d = lds + (size_t)(t & 1) * BUFU;
    #pragma unroll
    for (int c = 0; c < ACH; ++c) {
      int hc = h * ACH + c;
      gl_lds16(pA[hc] + (size_t)t * 64, d + hc * 4096 + tid * 8);
    }
  };
  auto stageB = [&](int t, int h) {      // B half h of tile t -> buf t&1
    u16* d = lds + (size_t)(t & 1) * BUFU + AU;
    #pragma unroll
    for (int c = 0; c < 2; ++c) {
      int hc = h * 2 + c;
      gl_lds16(pB[hc] + (size_t)t * 64, d + hc * 4096 + tid * 8);
    }
  };

  // prologue: A(0), B(0), B(1) staged; tile 0 verified landed
  stageA(0, 0); stageA(0, 1);
  stageB(0, 0); stageB(0, 1);
  stageB(1, 0); stageB(1, 1);
  waitvm<4>();                           // only B(1)'s 4 loads may remain
  barrier_np();

  for (int t = 0; t < NT; ++t) {
    const u16* buf = lds + (size_t)(t & 1) * BUFU;
    s16x8 bf[4][2];
    #pragma unroll
    for (int p = 0; p < 4; ++p) {
      if (p == 0) {
        #pragma unroll
        for (int j = 0; j < 4; ++j)
          #pragma unroll
          for (int s = 0; s < 2; ++s) bf[j][s] = *(const s16x8*)(buf + boff[j][s]);
      }
      s16x8 af[RT][2];
      #pragma unroll
      for (int i = 0; i < RT; ++i)
        #pragma unroll
        for (int s = 0; s < 2; ++s)
          af[i][s] = *(const s16x8*)(buf + aoff[p * RT + i][s]);
      if (p == 0) { if (t + 1 < NT) stageA(t + 1, 0); }
      if (p == 1) { if (t + 1 < NT) stageA(t + 1, 1); }
      if (p == 2) { if (t + 2 < NT) stageB(t + 2, 0); }
      if (p == 3) {
        if (t + 2 < NT) { stageB(t + 2, 1); waitvm<4>(); }
        else if (t + 1 < NT) { waitvm<0>(); }
      }
      barrier_np();
      __builtin_amdgcn_s_setprio(1);
      #pragma unroll
      for (int i = 0; i < RT; ++i)
        #pragma unroll
        for (int j = 0; j < 4; ++j)
          #pragma unroll
          for (int s = 0; s < 2; ++s)
            acc[p * RT + i][j] =
                __builtin_amdgcn_mfma_f32_16x16x32_bf16(af[i][s], bf[j][s], acc[p * RT + i][j], 0, 0, 0);
      __builtin_amdgcn_s_setprio(0);
      barrier_np();
    }
  }

  // epilogue: C/D layout col=lane&15, row=(lane>>4)*4+reg  (m89-verified)
  const int r0 = (lane >> 4) * 4;
  const int ccol = lane & 15;
  #pragma unroll
  for (int i = 0; i < MREP; ++i) {
    #pragma unroll
    for (int j = 0; j < 4; ++j) {
      #pragma unroll
      for (int r = 0; r < 4; ++r) {
        int R = m0 + wr * WR + i * 16 + r0 + r;           // row: (b,)s / q idx
        int C = n0 + wc * 64 + j * 16 + ccol;             // col: feature/k/d
        float v = acc[i][j][r];
        if constexpr (EPI == 0) {
          int sec = C >> 10, nl = C & 1023;
          v += (sec == 0) ? bq[nl] : (sec == 1) ? bk[nl] : bv[nl];
          u16 o = f2b(v);
          int b = R >> 11, s = R & 2047;
          if (sec == 0)      qw[(size_t)R * 1024 + nl] = o;               // Q[b][s][h]
          else if (sec == 1) kw[(size_t)R * 1024 + nl] = o;               // K[b][s][h]
          else               vt[(size_t)b * 2097152u + (size_t)nl * 2048 + s] = o; // Vt[b][d][s]
        } else if constexpr (EPI == 1) {
          v *= 0.03125f;  // 1/sqrt(1024)
          size_t idx = (size_t)(z * ze) + (size_t)R * 2048 + C;
          if (mask[idx] == 0) v = -__builtin_inff();
          sc[idx] = f2b(v);
        } else {
          outO[(size_t)(z * ze) + (size_t)R * 1024 + C] = v;   // fp32 out
        }
      }
    }
  }
}

// ---- row softmax over 2048 bf16, in place, fp32 internal --------------------
__global__ __launch_bounds__(256) void softmax_k(u16* __restrict__ Sc) {
  __shared__ float red[8];
  u16* p = Sc + (size_t)blockIdx.x * 2048;
  const int tid = threadIdx.x;
  const int lane = tid & 63, wv = tid >> 6;
  s16x8 u = *(const s16x8*)(p + tid * 8);
  float v[8];
  #pragma unroll
  for (int e = 0; e < 8; ++e) v[e] = b2f((u16)u[e]);
  float mx = v[0];
  #pragma unroll
  for (int e = 1; e < 8; ++e) mx = fmaxf(mx, v[e]);
  #pragma unroll
  for (int off = 32; off > 0; off >>= 1) mx = fmaxf(mx, __shfl_xor(mx, off));
  if (lane == 0) red[wv] = mx;
  __syncthreads();
  mx = fmaxf(fmaxf(red[0], red[1]), fmaxf(red[2], red[3]));
  float s = 0.f;
  #pragma unroll
  for (int e = 0; e < 8; ++e) { v[e] = __expf(v[e] - mx); s += v[e]; }
  #pragma unroll
  for (int off = 32; off > 0; off >>= 1) s += __shfl_xor(s, off);
  if (lane == 0) red[4 + wv] = s;
  __syncthreads();
  s = (red[4] + red[5]) + (red[6] + red[7]);
  float inv = 1.f / s;
  s16x8 o;
  #pragma unroll
  for (int e = 0; e < 8; ++e) o[e] = (short)f2b(v[e] * inv);
  *(s16x8*)(p + tid * 8) = o;
}

extern "C" void kernel_launch(void* const* d_in, const int* in_sizes, int n_in,
                              void* d_out, int out_size, void* d_ws, size_t ws_size,
                              hipStream_t stream) {
  const float* x  = (const float*)d_in[0];
  const int* mask = (const int*)d_in[1];
  const float* Wq = (const float*)d_in[2];
  const float* bq = (const float*)d_in[3];
  const float* Wk = (const float*)d_in[4];
  const float* bk = (const float*)d_in[5];
  const float* Wv = (const float*)d_in[6];
  const float* bv = (const float*)d_in[7];
  float* out = (float*)d_out;
  char* ws = (char*)d_ws;   // ws_size >= 104 MB established previously

  u16* xc  = (u16*)ws;                   // [8192][1024]  16 MB
  u16* Wqc = (u16*)(ws + (16u << 20));   // 2 MB each (contiguous after xc)
  u16* Wkc = (u16*)(ws + (18u << 20));
  u16* Wvc = (u16*)(ws + (20u << 20));
  u16* Qw  = (u16*)(ws + (22u << 20));   // [4][2048][1024] 16 MB
  u16* Kw  = (u16*)(ws + (38u << 20));   // 16 MB
  u16* Vt  = (u16*)(ws + (54u << 20));   // [4][1024][2048] 16 MB
  u16* Sc  = (u16*)(ws + (70u << 20));   // [4][2048][2048] 32 MB -> 102 MB

  convert4_k<<<5632, 256, 0, stream>>>(x, Wq, Wk, Wv, xc);

  // QKV: M=8192, N=3072, K=1024.  128x256 -> 768 blocks @1/CU = 3 exact rounds
  gemm_nt<0, 4><<<dim3(12, 64, 1), 512, 0, stream>>>(
      xc, Wqc, Wkc, Wvc, 1024, 1024, 1024, 0, 0, 0,
      bq, bk, bv, Qw, Kw, Vt, nullptr, nullptr, nullptr);
  // scores: per-z M=2048, N=2048, K=1024.  256x256 -> 256 blocks = 1 round
  gemm_nt<1, 8><<<dim3(8, 8, 4), 512, 0, stream>>>(
      Qw, Kw, nullptr, nullptr, 1024, 1024, 1024, 2097152, 2097152, 4194304,
      nullptr, nullptr, nullptr, nullptr, nullptr, nullptr, mask, Sc, nullptr);
  softmax_k<<<8192, 256, 0, stream>>>(Sc);
  // PV: per-z M=2048, N=1024, K=2048.  128x256 -> 256 blocks = 1 round
  gemm_nt<2, 4><<<dim3(4, 16, 4), 512, 0, stream>>>(
      Sc, Vt, nullptr, nullptr, 2048, 2048, 2048, 4194304, 2097152, 2097152,
      nullptr, nullptr, nullptr, nullptr, nullptr, nullptr, nullptr, nullptr, out);
}